// Round 2
// baseline (133.142 us; speedup 1.0000x reference)
//
#include <hip/hip_runtime.h>
#include <cstdint>

#define TDIM 8192   // B_*S_ = 4*2048 flattened tokens
#define MDIM 1024   // in_features (GEMM K)
#define NDIM 1024   // out_features
#define KBITS 8
#define BK 64       // K-depth per staging tile
#define BT 256      // token-rows per block
#define BN 128      // n-cols per block
#define NTILES (MDIM / BK)   // 16

typedef __bf16 bf16x8 __attribute__((ext_vector_type(8)));
typedef float f32x4 __attribute__((ext_vector_type(4)));

#define GAS(p) ((__attribute__((address_space(1))) void*)(uintptr_t)(p))
#define LAS(p) ((__attribute__((address_space(3))) void*)(uintptr_t)(p))

__device__ __forceinline__ unsigned short f2bf(float f) {
    union { float f; unsigned u; } v; v.f = f;
    unsigned r = v.u + 0x7fffu + ((v.u >> 16) & 1u);  // round-to-nearest-even
    return (unsigned short)(r >> 16);
}

// ---- W-fold only (x-cast moved into the gemm) ----
// 1024 blocks: Wt[n][m] = bf16( sum_k scale[k][n] * binary[k][m][n] ), 32x32 tiles,
// k fully unrolled so all 8 binary loads are in flight at once.
__global__ __launch_bounds__(256) void wfold_kernel(const float* __restrict__ binary,
                                                    const float* __restrict__ scale,
                                                    unsigned short* __restrict__ wtr) {
    __shared__ float tile[32][33];
    const int tid = threadIdx.x;
    const int n0 = (blockIdx.x & 31) * 32;
    const int m0 = (blockIdx.x >> 5) * 32;
    const int r = tid >> 3;
    const int cn = (tid & 7) * 4;
    f32x4 acc = {0.f, 0.f, 0.f, 0.f};
#pragma unroll
    for (int k = 0; k < KBITS; ++k) {
        f32x4 v = *(const f32x4*)(binary + ((size_t)k * MDIM + m0 + r) * NDIM + n0 + cn);
        f32x4 s = *(const f32x4*)(scale + (size_t)k * NDIM + n0 + cn);
        acc += v * s;
    }
#pragma unroll
    for (int e = 0; e < 4; ++e) tile[cn + e][r] = acc[e];
    __syncthreads();
    const int rn = tid >> 3;
    const int cm = (tid & 7) * 4;
    ushort4 o4;
    o4.x = f2bf(tile[rn][cm + 0]);
    o4.y = f2bf(tile[rn][cm + 1]);
    o4.z = f2bf(tile[rn][cm + 2]);
    o4.w = f2bf(tile[rn][cm + 3]);
    *(ushort4*)(wtr + (size_t)(n0 + rn) * MDIM + m0 + cm) = o4;
}

// ---- gemm: out[t][n] = sum_m bf16(x[t][m])*Wt[n][m] + bias[n] ----
// 256x128 tile, 8 waves (4Mx2N, per-wave 64x64), BK=64, double-buffered.
// A is reg-staged DIRECTLY from fp32 x with in-kernel bf16 cast (T14
// issue-early/write-late): tile t+1's 8 dwordx4 loads issue at the top of
// tile t, so the ~900cy HBM latency hides under the ~1240cy MFMA phase;
// the vmcnt(0)+pack+ds_write+barrier at tile end then finds data landed.
// This deletes the 48MB xb round-trip (prep x-read 32MB + xb write 16MB).
// B (wtr, 2MB, L2-resident) keeps global_load_lds. Same XOR-granule swizzle
// as the verified version, now applied on the ds_write side for A.
// grid (t=32, n=8): linear%8 == x%8 -> per XCD: 4 A-strips + all of B.
__global__ __launch_bounds__(512, 2) void gemm_kernel(const float* __restrict__ x,
                                                      const unsigned short* __restrict__ wtr,
                                                      const float* __restrict__ bias,
                                                      float* __restrict__ out) {
    constexpr int ASZ = BT * BK;        // 16384 elems (32 KB)
    constexpr int BSZ = BN * BK;        // 8192 elems  (16 KB)
    constexpr int BUF = ASZ + BSZ;      // 24576 elems (48 KB) per buffer
    __shared__ __attribute__((aligned(16))) unsigned short lds[2 * BUF];  // 96 KB

    const int tid = threadIdx.x;
    const int lane = tid & 63;
    const int wv = tid >> 6;        // 0..7
    const int wm = wv >> 1;         // 0..3 (64-row strip)
    const int wn = wv & 1;          // 0..1 (64-col strip)
    const int lrow = lane & 15;
    const int q = lane >> 4;

    const int t0 = blockIdx.x * BT;
    const int n0 = blockIdx.y * BN;

    // staging map: granule (16B bf16 / 32B fp32) s -> LDS slot s, holding global
    // granule (s&7)^(r&7) of row r = s>>3 (XOR swizzle, bank-conflict-free frag
    // reads -- verified in previous versions).
    const float* srcA[4];
    int dstA[4];
    const unsigned short* srcB[2];
    int dstB[2];
#pragma unroll
    for (int j = 0; j < 4; ++j) {
        int s = tid + j * 512;              // [0, 2048): 256 rows x 8 granules
        int r = s >> 3;
        int g = (s & 7) ^ (r & 7);
        srcA[j] = x + (size_t)(t0 + r) * MDIM + g * 8;   // fp32 source
        dstA[j] = s * 8;
    }
#pragma unroll
    for (int j = 0; j < 2; ++j) {
        int s = tid + j * 512;              // [0, 1024): 128 rows x 8 granules
        int r = s >> 3;
        int g = (s & 7) ^ (r & 7);
        srcB[j] = wtr + (size_t)(n0 + r) * MDIM + g * 8;
        dstB[j] = ASZ + s * 8;
    }

    // fragment LDS offsets: row m, k-half h, granule (h*4+q)^(m&7)
    int a_off[2][4], b_off[2][4];
#pragma unroll
    for (int h = 0; h < 2; ++h)
#pragma unroll
        for (int i = 0; i < 4; ++i) {
            int m = wm * 64 + i * 16 + lrow;
            a_off[h][i] = (m * 8 + ((h * 4 + q) ^ (m & 7))) * 8;
            int n = wn * 64 + i * 16 + lrow;
            b_off[h][i] = ASZ + (n * 8 + ((h * 4 + q) ^ (n & 7))) * 8;
        }

    f32x4 acc[4][4];
    const f32x4 zero = {0.f, 0.f, 0.f, 0.f};
#pragma unroll
    for (int i = 0; i < 4; ++i)
#pragma unroll
        for (int j = 0; j < 4; ++j) acc[i][j] = zero;

    f32x4 ar[4][2];   // one K-tile of A in flight (32 fp32/thread)

    auto issueA = [&](int t) {
        const int k0 = t * BK;
#pragma unroll
        for (int j = 0; j < 4; ++j) {
            ar[j][0] = *(const f32x4*)(srcA[j] + k0);
            ar[j][1] = *(const f32x4*)(srcA[j] + k0 + 4);
        }
    };
    auto issueB = [&](int bufsel, int t) {
        unsigned short* bb = lds + bufsel * BUF;
        const int k0 = t * BK;
#pragma unroll
        for (int j = 0; j < 2; ++j)
            __builtin_amdgcn_global_load_lds(GAS(srcB[j] + k0), LAS(bb + dstB[j]), 16, 0, 0);
    };
    auto writeA = [&](int bufsel) {
        unsigned short* bb = lds + bufsel * BUF;
#pragma unroll
        for (int j = 0; j < 4; ++j) {
            uint4 o;
            o.x = (unsigned)f2bf(ar[j][0][0]) | ((unsigned)f2bf(ar[j][0][1]) << 16);
            o.y = (unsigned)f2bf(ar[j][0][2]) | ((unsigned)f2bf(ar[j][0][3]) << 16);
            o.z = (unsigned)f2bf(ar[j][1][0]) | ((unsigned)f2bf(ar[j][1][1]) << 16);
            o.w = (unsigned)f2bf(ar[j][1][2]) | ((unsigned)f2bf(ar[j][1][3]) << 16);
            *(uint4*)(bb + dstA[j]) = o;
        }
    };

    // prologue: stage tile 0
    issueA(0);
    issueB(0, 0);
    asm volatile("s_waitcnt vmcnt(0)" ::: "memory");
    writeA(0);
    __syncthreads();

#pragma unroll
    for (int t = 0; t < NTILES; ++t) {
        const int cur = t & 1;
        // issue tile t+1's staging first: A-loads into regs (latency hides
        // under this tile's MFMAs), B direct-to-LDS into the free buffer.
        if (t + 1 < NTILES) {
            issueA(t + 1);
            issueB(cur ^ 1, t + 1);
        }

        const unsigned short* base = lds + cur * BUF;
#pragma unroll
        for (int h = 0; h < 2; ++h) {
            bf16x8 af[4], bfr[4];
#pragma unroll
            for (int i = 0; i < 4; ++i) af[i] = *(const bf16x8*)(base + a_off[h][i]);
#pragma unroll
            for (int i = 0; i < 4; ++i) bfr[i] = *(const bf16x8*)(base + b_off[h][i]);
            __builtin_amdgcn_s_setprio(1);
#pragma unroll
            for (int i = 0; i < 4; ++i)
#pragma unroll
                for (int j = 0; j < 4; ++j)
                    acc[i][j] = __builtin_amdgcn_mfma_f32_16x16x32_bf16(af[i], bfr[j],
                                                                        acc[i][j], 0, 0, 0);
            __builtin_amdgcn_s_setprio(0);
        }

        if (t + 1 < NTILES) {
            // loads were issued a full MFMA-phase ago -> drain is cheap.
            asm volatile("s_waitcnt vmcnt(0)" ::: "memory");
            writeA(cur ^ 1);
            __syncthreads();
        }
    }

    // epilogue: C/D layout col=lane&15 (n), row=q*4+reg (t). fuse bias.
#pragma unroll
    for (int j = 0; j < 4; ++j) {
        const int n = n0 + wn * 64 + j * 16 + lrow;
        const float bv = bias[n];
#pragma unroll
        for (int i = 0; i < 4; ++i) {
            const int tb = t0 + wm * 64 + i * 16 + q * 4;
#pragma unroll
            for (int r = 0; r < 4; ++r) {
                out[(size_t)(tb + r) * NDIM + n] = acc[i][j][r] + bv;
            }
        }
    }
}

extern "C" void kernel_launch(void* const* d_in, const int* in_sizes, int n_in,
                              void* d_out, int out_size, void* d_ws, size_t ws_size,
                              hipStream_t stream) {
    const float* x      = (const float*)d_in[0];   // [4,2048,1024] fp32
    const float* binary = (const float*)d_in[1];   // [8,1024,1024] fp32 (+/-1)
    const float* scale  = (const float*)d_in[2];   // [8,1,1024] fp32
    const float* bias   = (const float*)d_in[3];   // [1024] fp32
    float* out = (float*)d_out;                    // [4,2048,1024] fp32

    unsigned short* wtr = (unsigned short*)d_ws;   // 2 MB bf16 Wt[n][m]

    wfold_kernel<<<1024, 256, 0, stream>>>(binary, scale, wtr);
    gemm_kernel<<<dim3(TDIM / BT, NDIM / BN), 512, 0, stream>>>(x, wtr, bias, out);
}

// Round 3
// 123.878 us; speedup vs baseline: 1.0748x; 1.0748x over previous
//
#include <hip/hip_runtime.h>
#include <cstdint>

#define TDIM 8192   // B_*S_ = 4*2048 flattened tokens
#define MDIM 1024   // in_features (GEMM K)
#define NDIM 1024   // out_features
#define KBITS 8
#define BK 64       // K-depth per staging tile
#define BT 256      // token-rows per block
#define BN 128      // n-cols per block
#define NTILES (MDIM / BK)   // 16

typedef __bf16 bf16x8 __attribute__((ext_vector_type(8)));
typedef float f32x4 __attribute__((ext_vector_type(4)));

#define GAS(p) ((__attribute__((address_space(1))) void*)(uintptr_t)(p))
#define LAS(p) ((__attribute__((address_space(3))) void*)(uintptr_t)(p))

__device__ __forceinline__ unsigned short f2bf(float f) {
    union { float f; unsigned u; } v; v.f = f;
    unsigned r = v.u + 0x7fffu + ((v.u >> 16) & 1u);  // round-to-nearest-even
    return (unsigned short)(r >> 16);
}

// ---- fused prep (verified round-0 version) ----
// blocks [0,1024): W-fold 32x32 tiles: Wt[n][m] = bf16(sum_k scale[k][n]*binary[k][m][n])
// blocks [1024,5120): x fp32 -> bf16 cast, 8 elems/thread, coalesced.
__global__ __launch_bounds__(256) void prep_kernel(const float* __restrict__ x,
                                                   unsigned short* __restrict__ xb,
                                                   const float* __restrict__ binary,
                                                   const float* __restrict__ scale,
                                                   unsigned short* __restrict__ wtr) {
    __shared__ float tile[32][33];
    const int tid = threadIdx.x;
    if (blockIdx.x >= 1024) {
        size_t idx = ((size_t)(blockIdx.x - 1024) * 256 + tid) * 8;
        float4 a = *(const float4*)(x + idx);
        float4 b = *(const float4*)(x + idx + 4);
        uint4 o;
        o.x = (unsigned)f2bf(a.x) | ((unsigned)f2bf(a.y) << 16);
        o.y = (unsigned)f2bf(a.z) | ((unsigned)f2bf(a.w) << 16);
        o.z = (unsigned)f2bf(b.x) | ((unsigned)f2bf(b.y) << 16);
        o.w = (unsigned)f2bf(b.z) | ((unsigned)f2bf(b.w) << 16);
        *(uint4*)(xb + idx) = o;
        return;
    }
    const int n0 = (blockIdx.x & 31) * 32;
    const int m0 = (blockIdx.x >> 5) * 32;
    const int r = tid >> 3;
    const int cn = (tid & 7) * 4;
    f32x4 acc = {0.f, 0.f, 0.f, 0.f};
#pragma unroll
    for (int k = 0; k < KBITS; ++k) {
        f32x4 v = *(const f32x4*)(binary + ((size_t)k * MDIM + m0 + r) * NDIM + n0 + cn);
        f32x4 s = *(const f32x4*)(scale + (size_t)k * NDIM + n0 + cn);
        acc += v * s;
    }
#pragma unroll
    for (int e = 0; e < 4; ++e) tile[cn + e][r] = acc[e];
    __syncthreads();
    const int rn = tid >> 3;
    const int cm = (tid & 7) * 4;
    ushort4 o4;
    o4.x = f2bf(tile[rn][cm + 0]);
    o4.y = f2bf(tile[rn][cm + 1]);
    o4.z = f2bf(tile[rn][cm + 2]);
    o4.w = f2bf(tile[rn][cm + 3]);
    *(ushort4*)(wtr + (size_t)(n0 + rn) * MDIM + m0 + cm) = o4;
}

// ---- gemm: out[t][n] = sum_m xb[t][m]*Wt[n][m] + bias[n] ----
// 256x128 tile, 8 waves (4Mx2N, per-wave 64x64), BK=64, triple-buffered
// global_load_lds staging with the 8-PHASE interleave (T3+T4+T5):
// per K-tile, 2 phases of {8 ds_read_b128 + 3 gload_lds issue -> s_barrier ->
// lgkmcnt(0) -> setprio(1) 16 MFMA setprio(0) -> s_barrier}; vmcnt(6) ONLY at
// the tile boundary (2 tiles of staging in flight, never drained to 0 mid-loop).
// Same verified XOR-granule swizzle + epilogue as previous passing versions.
// grid (t=32, n=8): linear%8 == x%8 -> per XCD: 4 A-strips + all of B L2-resident.
__global__ __launch_bounds__(512, 2) void gemm_kernel(const unsigned short* __restrict__ xb,
                                                      const unsigned short* __restrict__ wtr,
                                                      const float* __restrict__ bias,
                                                      float* __restrict__ out) {
    constexpr int ASZ = BT * BK;        // 16384 elems (32 KB)
    constexpr int BSZ = BN * BK;        // 8192 elems  (16 KB)
    constexpr int BUF = ASZ + BSZ;      // 24576 elems (48 KB) per buffer
    __shared__ __attribute__((aligned(16))) unsigned short lds[3 * BUF];  // 144 KB

    const int tid = threadIdx.x;
    const int lane = tid & 63;
    const int wv = tid >> 6;        // 0..7
    const int wm = wv >> 1;         // 0..3 (64-row strip)
    const int wn = wv & 1;          // 0..1 (64-col strip)
    const int lrow = lane & 15;
    const int q = lane >> 4;

    const int t0 = blockIdx.x * BT;
    const int n0 = blockIdx.y * BN;

    // staging map: granule (16B) s -> LDS slot s, holding global granule
    // (s&7)^(r&7) of row r = s>>3 (XOR swizzle; bank-conflict-free, verified).
    const unsigned short* srcA[4];
    int dstA[4];
    const unsigned short* srcB[2];
    int dstB[2];
#pragma unroll
    for (int j = 0; j < 4; ++j) {
        int s = tid + j * 512;              // [0, 2048): 256 rows x 8 granules
        int r = s >> 3;
        int g = (s & 7) ^ (r & 7);
        srcA[j] = xb + (size_t)(t0 + r) * MDIM + g * 8;
        dstA[j] = s * 8;
    }
#pragma unroll
    for (int j = 0; j < 2; ++j) {
        int s = tid + j * 512;              // [0, 1024): 128 rows x 8 granules
        int r = s >> 3;
        int g = (s & 7) ^ (r & 7);
        srcB[j] = wtr + (size_t)(n0 + r) * MDIM + g * 8;
        dstB[j] = ASZ + s * 8;
    }

    // fragment LDS offsets: row m, k-half h, granule (h*4+q)^(m&7)
    int a_off[2][4], b_off[2][4];
#pragma unroll
    for (int h = 0; h < 2; ++h)
#pragma unroll
        for (int i = 0; i < 4; ++i) {
            int m = wm * 64 + i * 16 + lrow;
            a_off[h][i] = (m * 8 + ((h * 4 + q) ^ (m & 7))) * 8;
            int n = wn * 64 + i * 16 + lrow;
            b_off[h][i] = ASZ + (n * 8 + ((h * 4 + q) ^ (n & 7))) * 8;
        }

    f32x4 acc[4][4];
    const f32x4 zero = {0.f, 0.f, 0.f, 0.f};
#pragma unroll
    for (int i = 0; i < 4; ++i)
#pragma unroll
        for (int j = 0; j < 4; ++j) acc[i][j] = zero;

    auto stage_all = [&](int bufsel, int t) {
        unsigned short* bb = lds + bufsel * BUF;
        const int k0 = t * BK;
#pragma unroll
        for (int j = 0; j < 4; ++j)
            __builtin_amdgcn_global_load_lds(GAS(srcA[j] + k0), LAS(bb + dstA[j]), 16, 0, 0);
#pragma unroll
        for (int j = 0; j < 2; ++j)
            __builtin_amdgcn_global_load_lds(GAS(srcB[j] + k0), LAS(bb + dstB[j]), 16, 0, 0);
    };

    // prologue: tiles 0 and 1 staged; wait until tile 0's 6 landed (tile 1's
    // 6 stay in flight).
    stage_all(0, 0);
    stage_all(1, 1);
    asm volatile("s_waitcnt vmcnt(6)" ::: "memory");
    __builtin_amdgcn_s_barrier();
    __builtin_amdgcn_sched_barrier(0);

#pragma unroll
    for (int t = 0; t < NTILES; ++t) {
        const unsigned short* base = lds + (t % 3) * BUF;
        unsigned short* sbuf = lds + ((t + 2) % 3) * BUF;
        const int k2 = (t + 2) * BK;
        const bool prefetch = (t + 2 < NTILES);

        // ================= phase 0 (k-half 0) =================
        {
            bf16x8 af[4], bfr[4];
#pragma unroll
            for (int i = 0; i < 4; ++i) af[i] = *(const bf16x8*)(base + a_off[0][i]);
#pragma unroll
            for (int i = 0; i < 4; ++i) bfr[i] = *(const bf16x8*)(base + b_off[0][i]);
            if (prefetch) {
#pragma unroll
                for (int j = 0; j < 3; ++j)
                    __builtin_amdgcn_global_load_lds(GAS(srcA[j] + k2),
                                                     LAS(sbuf + dstA[j]), 16, 0, 0);
            }
            __builtin_amdgcn_s_barrier();
            asm volatile("s_waitcnt lgkmcnt(0)" ::: "memory");
            __builtin_amdgcn_sched_barrier(0);
            __builtin_amdgcn_s_setprio(1);
#pragma unroll
            for (int i = 0; i < 4; ++i)
#pragma unroll
                for (int j = 0; j < 4; ++j)
                    acc[i][j] = __builtin_amdgcn_mfma_f32_16x16x32_bf16(af[i], bfr[j],
                                                                        acc[i][j], 0, 0, 0);
            __builtin_amdgcn_s_setprio(0);
            __builtin_amdgcn_s_barrier();
            __builtin_amdgcn_sched_barrier(0);
        }

        // ================= phase 1 (k-half 1) =================
        {
            bf16x8 af[4], bfr[4];
#pragma unroll
            for (int i = 0; i < 4; ++i) af[i] = *(const bf16x8*)(base + a_off[1][i]);
#pragma unroll
            for (int i = 0; i < 4; ++i) bfr[i] = *(const bf16x8*)(base + b_off[1][i]);
            if (prefetch) {
                __builtin_amdgcn_global_load_lds(GAS(srcA[3] + k2),
                                                 LAS(sbuf + dstA[3]), 16, 0, 0);
#pragma unroll
                for (int j = 0; j < 2; ++j)
                    __builtin_amdgcn_global_load_lds(GAS(srcB[j] + k2),
                                                     LAS(sbuf + dstB[j]), 16, 0, 0);
            }
            __builtin_amdgcn_s_barrier();
            asm volatile("s_waitcnt lgkmcnt(0)" ::: "memory");
            __builtin_amdgcn_sched_barrier(0);
            __builtin_amdgcn_s_setprio(1);
#pragma unroll
            for (int i = 0; i < 4; ++i)
#pragma unroll
                for (int j = 0; j < 4; ++j)
                    acc[i][j] = __builtin_amdgcn_mfma_f32_16x16x32_bf16(af[i], bfr[j],
                                                                        acc[i][j], 0, 0, 0);
            __builtin_amdgcn_s_setprio(0);
        }

        // ---- tile boundary: counted wait (never 0 while prefetch remains) ----
        if (t + 1 < NTILES) {
            if (t + 2 < NTILES) {
                asm volatile("s_waitcnt vmcnt(6)" ::: "memory");   // t+1 landed, t+2 in flight
            } else {
                asm volatile("s_waitcnt vmcnt(0)" ::: "memory");   // tail drain
            }
            __builtin_amdgcn_s_barrier();
            __builtin_amdgcn_sched_barrier(0);
        }
    }

    // epilogue: C/D layout col=lane&15 (n), row=q*4+reg (t). fuse bias.
#pragma unroll
    for (int j = 0; j < 4; ++j) {
        const int n = n0 + wn * 64 + j * 16 + lrow;
        const float bv = bias[n];
#pragma unroll
        for (int i = 0; i < 4; ++i) {
            const int tb = t0 + wm * 64 + i * 16 + q * 4;
#pragma unroll
            for (int r = 0; r < 4; ++r) {
                out[(size_t)(tb + r) * NDIM + n] = acc[i][j][r] + bv;
            }
        }
    }
}

extern "C" void kernel_launch(void* const* d_in, const int* in_sizes, int n_in,
                              void* d_out, int out_size, void* d_ws, size_t ws_size,
                              hipStream_t stream) {
    const float* x      = (const float*)d_in[0];   // [4,2048,1024] fp32
    const float* binary = (const float*)d_in[1];   // [8,1024,1024] fp32 (+/-1)
    const float* scale  = (const float*)d_in[2];   // [8,1,1024] fp32
    const float* bias   = (const float*)d_in[3];   // [1024] fp32
    float* out = (float*)d_out;                    // [4,2048,1024] fp32

    unsigned short* xb  = (unsigned short*)d_ws;            // 16 MB bf16 x
    unsigned short* wtr = xb + (size_t)TDIM * MDIM;         // 2 MB bf16 Wt[n][m]

    prep_kernel<<<1024 + 4096, 256, 0, stream>>>(x, xb, binary, scale, wtr);
    gemm_kernel<<<dim3(TDIM / BT, NDIM / BN), 512, 0, stream>>>(xb, wtr, bias, out);
}

// Round 4
// 122.676 us; speedup vs baseline: 1.0853x; 1.0098x over previous
//
#include <hip/hip_runtime.h>
#include <cstdint>

#define TDIM 8192   // B_*S_ = 4*2048 flattened tokens
#define MDIM 1024   // in_features (GEMM K)
#define NDIM 1024   // out_features
#define KBITS 8
#define BK 64       // K-depth per staging tile
#define BT 128      // token-rows per block
#define BN 128      // n-cols per block
#define NTILES (MDIM / BK)   // 16

typedef __bf16 bf16x8 __attribute__((ext_vector_type(8)));
typedef float f32x4 __attribute__((ext_vector_type(4)));

#define GAS(p) ((__attribute__((address_space(1))) void*)(uintptr_t)(p))
#define LAS(p) ((__attribute__((address_space(3))) void*)(uintptr_t)(p))

__device__ __forceinline__ unsigned short f2bf(float f) {
    union { float f; unsigned u; } v; v.f = f;
    unsigned r = v.u + 0x7fffu + ((v.u >> 16) & 1u);  // round-to-nearest-even
    return (unsigned short)(r >> 16);
}

// ---- fused prep (verified) ----
// blocks [0,1024): W-fold 32x32 tiles: Wt[n][m] = bf16(sum_k scale[k][n]*binary[k][m][n])
// blocks [1024,5120): x fp32 -> bf16 cast, 8 elems/thread, coalesced.
__global__ __launch_bounds__(256) void prep_kernel(const float* __restrict__ x,
                                                   unsigned short* __restrict__ xb,
                                                   const float* __restrict__ binary,
                                                   const float* __restrict__ scale,
                                                   unsigned short* __restrict__ wtr) {
    __shared__ float tile[32][33];
    const int tid = threadIdx.x;
    if (blockIdx.x >= 1024) {
        size_t idx = ((size_t)(blockIdx.x - 1024) * 256 + tid) * 8;
        float4 a = *(const float4*)(x + idx);
        float4 b = *(const float4*)(x + idx + 4);
        uint4 o;
        o.x = (unsigned)f2bf(a.x) | ((unsigned)f2bf(a.y) << 16);
        o.y = (unsigned)f2bf(a.z) | ((unsigned)f2bf(a.w) << 16);
        o.z = (unsigned)f2bf(b.x) | ((unsigned)f2bf(b.y) << 16);
        o.w = (unsigned)f2bf(b.z) | ((unsigned)f2bf(b.w) << 16);
        *(uint4*)(xb + idx) = o;
        return;
    }
    const int n0 = (blockIdx.x & 31) * 32;
    const int m0 = (blockIdx.x >> 5) * 32;
    const int r = tid >> 3;
    const int cn = (tid & 7) * 4;
    f32x4 acc = {0.f, 0.f, 0.f, 0.f};
#pragma unroll
    for (int k = 0; k < KBITS; ++k) {
        f32x4 v = *(const f32x4*)(binary + ((size_t)k * MDIM + m0 + r) * NDIM + n0 + cn);
        f32x4 s = *(const f32x4*)(scale + (size_t)k * NDIM + n0 + cn);
        acc += v * s;
    }
#pragma unroll
    for (int e = 0; e < 4; ++e) tile[cn + e][r] = acc[e];
    __syncthreads();
    const int rn = tid >> 3;
    const int cm = (tid & 7) * 4;
    ushort4 o4;
    o4.x = f2bf(tile[rn][cm + 0]);
    o4.y = f2bf(tile[rn][cm + 1]);
    o4.z = f2bf(tile[rn][cm + 2]);
    o4.w = f2bf(tile[rn][cm + 3]);
    *(ushort4*)(wtr + (size_t)(n0 + rn) * MDIM + m0 + cm) = o4;
}

// ---- gemm: out[t][n] = sum_m xb[t][m]*Wt[n][m] + bias[n] ----
// 128x128 tile, 4 waves (2Mx2N, per-wave 64x64), BK=64, DOUBLE-buffered (64KB
// LDS) -> 2 blocks/CU (the m114 mechanism: a co-resident block covers the
// other's barrier drain, prologue latency, and epilogue write burst -- absent
// in the 1-block/CU r1/r3 variants that all plateaued at ~20% MfmaUtil).
// Staging for tile t+1 is issued at the TOP of tile t (a full compute phase
// before the boundary __syncthreads drains it). Verified XOR-granule swizzle,
// fragment math, and epilogue carried over unchanged.
// grid (t=64, n=8): 64%8==0 -> linear%8 == x%8: per XCD 8 A-strips (2MB) +
// all of B (2MB) stay L2-resident.
__global__ __launch_bounds__(256, 2) void gemm_kernel(const unsigned short* __restrict__ xb,
                                                      const unsigned short* __restrict__ wtr,
                                                      const float* __restrict__ bias,
                                                      float* __restrict__ out) {
    constexpr int ASZ = BT * BK;        // 8192 elems (16 KB)
    constexpr int BSZ = BN * BK;        // 8192 elems (16 KB)
    constexpr int BUF = ASZ + BSZ;      // 16384 elems (32 KB) per buffer
    __shared__ __attribute__((aligned(16))) unsigned short lds[2 * BUF];  // 64 KB

    const int tid = threadIdx.x;
    const int lane = tid & 63;
    const int wv = tid >> 6;        // 0..3
    const int wm = wv >> 1;         // 0..1 (64-row strip)
    const int wn = wv & 1;          // 0..1 (64-col strip)
    const int lrow = lane & 15;
    const int q = lane >> 4;

    const int t0 = blockIdx.x * BT;
    const int n0 = blockIdx.y * BN;

    // staging map: granule (16B) s -> LDS slot s, holding global granule
    // (s&7)^(r&7) of row r = s>>3 (XOR swizzle; bank-conflict-free, verified).
    const unsigned short* srcA[4];
    int dstA[4];
    const unsigned short* srcB[4];
    int dstB[4];
#pragma unroll
    for (int j = 0; j < 4; ++j) {
        int s = tid + j * 256;              // [0, 1024): 128 rows x 8 granules
        int r = s >> 3;
        int g = (s & 7) ^ (r & 7);
        srcA[j] = xb + (size_t)(t0 + r) * MDIM + g * 8;
        dstA[j] = s * 8;
        srcB[j] = wtr + (size_t)(n0 + r) * MDIM + g * 8;
        dstB[j] = ASZ + s * 8;
    }

    // fragment LDS offsets: row m, k-half h, granule (h*4+q)^(m&7)
    int a_off[2][4], b_off[2][4];
#pragma unroll
    for (int h = 0; h < 2; ++h)
#pragma unroll
        for (int i = 0; i < 4; ++i) {
            int m = wm * 64 + i * 16 + lrow;
            a_off[h][i] = (m * 8 + ((h * 4 + q) ^ (m & 7))) * 8;
            int n = wn * 64 + i * 16 + lrow;
            b_off[h][i] = ASZ + (n * 8 + ((h * 4 + q) ^ (n & 7))) * 8;
        }

    f32x4 acc[4][4];
    const f32x4 zero = {0.f, 0.f, 0.f, 0.f};
#pragma unroll
    for (int i = 0; i < 4; ++i)
#pragma unroll
        for (int j = 0; j < 4; ++j) acc[i][j] = zero;

    auto stage = [&](int bufsel, int t) {
        unsigned short* bb = lds + bufsel * BUF;
        const int k0 = t * BK;
#pragma unroll
        for (int j = 0; j < 4; ++j)
            __builtin_amdgcn_global_load_lds(GAS(srcA[j] + k0), LAS(bb + dstA[j]), 16, 0, 0);
#pragma unroll
        for (int j = 0; j < 4; ++j)
            __builtin_amdgcn_global_load_lds(GAS(srcB[j] + k0), LAS(bb + dstB[j]), 16, 0, 0);
    };

    // prologue: stage tile 0, drain, go.
    stage(0, 0);
    __syncthreads();

#pragma unroll
    for (int t = 0; t < NTILES; ++t) {
        const int cur = t & 1;
        // issue tile t+1's staging first: its HBM/L2 latency hides under this
        // tile's ds_reads + MFMAs; the boundary __syncthreads then drains it.
        if (t + 1 < NTILES) stage(cur ^ 1, t + 1);

        const unsigned short* base = lds + cur * BUF;
#pragma unroll
        for (int h = 0; h < 2; ++h) {
            bf16x8 af[4], bfr[4];
#pragma unroll
            for (int i = 0; i < 4; ++i) af[i] = *(const bf16x8*)(base + a_off[h][i]);
#pragma unroll
            for (int i = 0; i < 4; ++i) bfr[i] = *(const bf16x8*)(base + b_off[h][i]);
            __builtin_amdgcn_s_setprio(1);
#pragma unroll
            for (int i = 0; i < 4; ++i)
#pragma unroll
                for (int j = 0; j < 4; ++j)
                    acc[i][j] = __builtin_amdgcn_mfma_f32_16x16x32_bf16(af[i], bfr[j],
                                                                        acc[i][j], 0, 0, 0);
            __builtin_amdgcn_s_setprio(0);
        }

        if (t + 1 < NTILES) __syncthreads();
    }

    // epilogue: C/D layout col=lane&15 (n), row=q*4+reg (t). fuse bias.
#pragma unroll
    for (int j = 0; j < 4; ++j) {
        const int n = n0 + wn * 64 + j * 16 + lrow;
        const float bv = bias[n];
#pragma unroll
        for (int i = 0; i < 4; ++i) {
            const int tb = t0 + wm * 64 + i * 16 + q * 4;
#pragma unroll
            for (int r = 0; r < 4; ++r) {
                out[(size_t)(tb + r) * NDIM + n] = acc[i][j][r] + bv;
            }
        }
    }
}

extern "C" void kernel_launch(void* const* d_in, const int* in_sizes, int n_in,
                              void* d_out, int out_size, void* d_ws, size_t ws_size,
                              hipStream_t stream) {
    const float* x      = (const float*)d_in[0];   // [4,2048,1024] fp32
    const float* binary = (const float*)d_in[1];   // [8,1024,1024] fp32 (+/-1)
    const float* scale  = (const float*)d_in[2];   // [8,1,1024] fp32
    const float* bias   = (const float*)d_in[3];   // [1024] fp32
    float* out = (float*)d_out;                    // [4,2048,1024] fp32

    unsigned short* xb  = (unsigned short*)d_ws;            // 16 MB bf16 x
    unsigned short* wtr = xb + (size_t)TDIM * MDIM;         // 2 MB bf16 Wt[n][m]

    prep_kernel<<<1024 + 4096, 256, 0, stream>>>(x, xb, binary, scale, wtr);
    gemm_kernel<<<dim3(TDIM / BT, NDIM / BN), 256, 0, stream>>>(xb, wtr, bias, out);
}